// Round 1
// baseline (757.384 us; speedup 1.0000x reference)
//
#include <hip/hip_runtime.h>
#include <stdint.h>

#define SLEN 2048
#define BSZ  2
#define HSZ  1024
#define FFND 4096
#define NEXP 8
#define TOPK 2
#define NTOK (SLEN*BSZ)        // 4096
#define NSLOT (NTOK*TOPK)      // 8192

#define BM 128
#define BN 128
#define BK 32
#define SA 40    // A_lds row stride (elems): BK + 8 pad -> b128 reads <=2-way
#define SW 130   // W_lds row stride (elems): BN + 2 pad -> u16 frag reads conflict-free

using short8 = __attribute__((ext_vector_type(8))) short;
using f32x4  = __attribute__((ext_vector_type(4))) float;

__device__ inline unsigned short f2bf(float f){
  unsigned u = __builtin_bit_cast(unsigned, f);
  u += 0x7FFFu + ((u >> 16) & 1u);      // round-to-nearest-even
  return (unsigned short)(u >> 16);
}

__device__ inline float gelu_tanh(float x){
  // jax.nn.gelu default (approximate=True)
  float u = 0.7978845608028654f * (x + 0.044715f * x * x * x);
  return 0.5f * x * (1.0f + tanhf(u));
}

// ---------------- routing kernels ----------------

__global__ void k_count(const int* __restrict__ ei, int* __restrict__ counts){
  int i = blockIdx.x * blockDim.x + threadIdx.x;
  if (i < NSLOT) atomicAdd(&counts[ei[i]], 1);
}

__global__ void k_scan(const int* __restrict__ counts, int* __restrict__ offsets,
                       int* __restrict__ fill){
  if (threadIdx.x == 0 && blockIdx.x == 0){
    int acc = 0;
    for (int e = 0; e < NEXP; e++){ offsets[e] = acc; fill[e] = acc; acc += counts[e]; }
  }
}

__global__ void k_assign(const int* __restrict__ ei, const float* __restrict__ ew,
                         int* __restrict__ fill, int* __restrict__ rowT,
                         float* __restrict__ rowC){
  int i = blockIdx.x * blockDim.x + threadIdx.x;
  if (i < NSLOT){
    int e = ei[i];
    int slot = atomicAdd(&fill[e], 1);
    rowT[slot] = i >> 1;       // token index (i = t*TOPK + k)
    rowC[slot] = ew[i];
  }
}

__global__ void k_gather(const float* __restrict__ x, const int* __restrict__ rowT,
                         unsigned short* __restrict__ Xg){
  int slot = blockIdx.x;
  int t = rowT[slot];
  int c = threadIdx.x * 4;
  float4 v = *(const float4*)(x + (size_t)t * HSZ + c);
  ushort4 o;
  o.x = f2bf(v.x); o.y = f2bf(v.y); o.z = f2bf(v.z); o.w = f2bf(v.w);
  *(ushort4*)(Xg + (size_t)slot * HSZ + c) = o;
}

// ---------------- GEMM core ----------------
// A: bf16 [rows x K] row-major (k-contiguous), lda elems.
// B: fp32 [K x ldb] row-major, pre-offset to column n0; staged->bf16 in LDS.
// Each block: 128x128 tile; 4 waves in 2x2, each wave 4x4 of 16x16x32 mfma.
__device__ inline void gemm_core(const unsigned short* __restrict__ Ag, int lda, int rows,
                                 const float* __restrict__ Bg, int ldb, int K,
                                 unsigned short* As, unsigned short* Ws,
                                 f32x4 acc[4][4])
{
  const int tid  = threadIdx.x;
  const int lane = tid & 63;
  const int wid  = tid >> 6;
  const int wm   = (wid & 1) * 64;
  const int wn   = (wid >> 1) * 64;
  const int q    = lane >> 4;
  const int l16  = lane & 15;

  for (int k0 = 0; k0 < K; k0 += BK){
    // stage A tile [BM x BK] (zero-fill tail rows)
    #pragma unroll
    for (int p = 0; p < 2; p++){
      int r  = p * 64 + (tid >> 2);
      int kk = (tid & 3) * 8;
      uint4 v = make_uint4(0u, 0u, 0u, 0u);
      if (r < rows) v = *(const uint4*)(Ag + (size_t)r * lda + k0 + kk);
      *(uint4*)(As + r * SA + kk) = v;
    }
    // stage B tile [BK x BN], fp32 -> bf16
    #pragma unroll
    for (int p = 0; p < 4; p++){
      int kk = p * 8 + (tid >> 5);
      int c  = (tid & 31) * 4;
      float4 v = *(const float4*)(Bg + (size_t)(k0 + kk) * ldb + c);
      unsigned lo = (unsigned)f2bf(v.x) | ((unsigned)f2bf(v.y) << 16);
      unsigned hi = (unsigned)f2bf(v.z) | ((unsigned)f2bf(v.w) << 16);
      *(unsigned*)(Ws + kk * SW + c)     = lo;
      *(unsigned*)(Ws + kk * SW + c + 2) = hi;
    }
    __syncthreads();

    short8 af[4], bfr[4];
    #pragma unroll
    for (int i = 0; i < 4; i++)
      af[i] = *(const short8*)(As + (wm + i * 16 + l16) * SA + q * 8);
    #pragma unroll
    for (int j = 0; j < 4; j++){
      short8 b;
      #pragma unroll
      for (int jj = 0; jj < 8; jj++)
        b[jj] = (short)Ws[(q * 8 + jj) * SW + wn + j * 16 + l16];
      bfr[j] = b;
    }
    #pragma unroll
    for (int i = 0; i < 4; i++)
      #pragma unroll
      for (int j = 0; j < 4; j++)
        acc[i][j] = __builtin_amdgcn_mfma_f32_16x16x32_bf16(af[i], bfr[j], acc[i][j], 0, 0, 0);
    __syncthreads();
  }
}

// ---------------- GEMM1: H = gelu(Xg @ w1[e]) ----------------
__global__ __launch_bounds__(256) void k_gemm1(const unsigned short* __restrict__ Xg,
                                               const float* __restrict__ w1,
                                               unsigned short* __restrict__ H,
                                               const int* __restrict__ counts,
                                               const int* __restrict__ offsets)
{
  __shared__ unsigned short As[BM * SA];
  __shared__ unsigned short Ws[BK * SW];
  const int e    = blockIdx.z;
  const int cnt  = counts[e];
  const int mblk = blockIdx.y;
  if (mblk * BM >= cnt) return;
  const int n0   = blockIdx.x * BN;
  const int row0 = offsets[e] + mblk * BM;
  const int rows = min(BM, cnt - mblk * BM);

  f32x4 acc[4][4] = {};
  gemm_core(Xg + (size_t)row0 * HSZ, HSZ, rows,
            w1 + (size_t)e * HSZ * FFND + n0, FFND, HSZ, As, Ws, acc);

  const int lane = threadIdx.x & 63, wid = threadIdx.x >> 6;
  const int wm = (wid & 1) * 64, wn = (wid >> 1) * 64;
  const int q = lane >> 4, l16 = lane & 15;
  #pragma unroll
  for (int i = 0; i < 4; i++)
    #pragma unroll
    for (int j = 0; j < 4; j++)
      #pragma unroll
      for (int r = 0; r < 4; r++){
        int row = wm + i * 16 + q * 4 + r;      // C/D: row=(lane>>4)*4+reg
        if (row < rows){
          int col = wn + j * 16 + l16;          // C/D: col=lane&15
          H[(size_t)(row0 + row) * FFND + n0 + col] = f2bf(gelu_tanh(acc[i][j][r]));
        }
      }
}

// ---------------- GEMM2: out[t] += coef * (H @ w2[e]) ----------------
__global__ __launch_bounds__(256) void k_gemm2(const unsigned short* __restrict__ H,
                                               const float* __restrict__ w2,
                                               float* __restrict__ out,
                                               const int* __restrict__ counts,
                                               const int* __restrict__ offsets,
                                               const int* __restrict__ rowT,
                                               const float* __restrict__ rowC)
{
  __shared__ unsigned short As[BM * SA];
  __shared__ unsigned short Ws[BK * SW];
  const int e    = blockIdx.z;
  const int cnt  = counts[e];
  const int mblk = blockIdx.y;
  if (mblk * BM >= cnt) return;
  const int n0   = blockIdx.x * BN;
  const int row0 = offsets[e] + mblk * BM;
  const int rows = min(BM, cnt - mblk * BM);

  f32x4 acc[4][4] = {};
  gemm_core(H + (size_t)row0 * FFND, FFND, rows,
            w2 + (size_t)e * FFND * HSZ + n0, HSZ, FFND, As, Ws, acc);

  const int lane = threadIdx.x & 63, wid = threadIdx.x >> 6;
  const int wm = (wid & 1) * 64, wn = (wid >> 1) * 64;
  const int q = lane >> 4, l16 = lane & 15;
  #pragma unroll
  for (int i = 0; i < 4; i++)
    #pragma unroll
    for (int j = 0; j < 4; j++)
      #pragma unroll
      for (int r = 0; r < 4; r++){
        int row = wm + i * 16 + q * 4 + r;
        if (row < rows){
          int g = row0 + row;
          int col = wn + j * 16 + l16;
          atomicAdd(out + (size_t)rowT[g] * HSZ + n0 + col, rowC[g] * acc[i][j][r]);
        }
      }
}

// ---------------- launch ----------------
extern "C" void kernel_launch(void* const* d_in, const int* in_sizes, int n_in,
                              void* d_out, int out_size, void* d_ws, size_t ws_size,
                              hipStream_t stream) {
  const float* x  = (const float*)d_in[0];
  const float* ew = (const float*)d_in[1];
  const int*   ei = (const int*)d_in[2];
  const float* w1 = (const float*)d_in[3];
  const float* w2 = (const float*)d_in[4];
  float* out = (float*)d_out;

  // workspace layout
  int*   counts  = (int*)d_ws;                       // 8
  int*   fill    = counts + 8;                       // 8
  int*   offsets = fill + 8;                         // 8
  int*   rowT    = offsets + 8;                      // 8192
  float* rowC    = (float*)(rowT + NSLOT);           // 8192
  unsigned short* Xg = (unsigned short*)(rowC + NSLOT);        // 8192*1024 bf16
  unsigned short* H  = Xg + (size_t)NSLOT * HSZ;               // 8192*4096 bf16

  hipMemsetAsync(d_out, 0, (size_t)out_size * sizeof(float), stream);
  hipMemsetAsync(counts, 0, 8 * sizeof(int), stream);

  k_count <<<NSLOT / 256, 256, 0, stream>>>(ei, counts);
  k_scan  <<<1, 64, 0, stream>>>(counts, offsets, fill);
  k_assign<<<NSLOT / 256, 256, 0, stream>>>(ei, ew, fill, rowT, rowC);
  k_gather<<<NSLOT, 256, 0, stream>>>(x, rowT, Xg);

  // worst case one expert owns all 8192 rows -> 64 m-blocks; extras early-exit
  k_gemm1<<<dim3(FFND / BN, 64, NEXP), 256, 0, stream>>>(Xg, w1, H, counts, offsets);
  k_gemm2<<<dim3(HSZ  / BN, 64, NEXP), 256, 0, stream>>>(H, w2, out, counts, offsets, rowT, rowC);
}

// Round 2
// 679.800 us; speedup vs baseline: 1.1141x; 1.1141x over previous
//
#include <hip/hip_runtime.h>
#include <stdint.h>

#define SLEN 2048
#define BSZ  2
#define HSZ  1024
#define FFND 4096
#define NEXP 8
#define TOPK 2
#define NTOK (SLEN*BSZ)        // 4096
#define NSLOT (NTOK*TOPK)      // 8192

#define BM 128
#define BN 128
#define BK 32

using short8 = __attribute__((ext_vector_type(8))) short;
using f32x4  = __attribute__((ext_vector_type(4))) float;

typedef __attribute__((address_space(1))) const unsigned int gu32;
typedef __attribute__((address_space(3))) unsigned int lu32;

__device__ inline void async_copy16(const void* g, void* l){
  // DMA 16B/lane global->LDS; LDS dest = wave-uniform base + lane*16
  __builtin_amdgcn_global_load_lds((gu32*)g, (lu32*)l, 16, 0, 0);
}

__device__ inline unsigned short f2bf(float f){
  unsigned u = __builtin_bit_cast(unsigned, f);
  u += 0x7FFFu + ((u >> 16) & 1u);      // round-to-nearest-even
  return (unsigned short)(u >> 16);
}

__device__ inline float gelu_tanh(float x){
  // jax.nn.gelu default (approximate=True)
  float u = 0.7978845608028654f * (x + 0.044715f * x * x * x);
  return 0.5f * x * (1.0f + tanhf(u));
}

// ---------------- routing kernels ----------------

__global__ void k_count(const int* __restrict__ ei, int* __restrict__ counts){
  int i = blockIdx.x * blockDim.x + threadIdx.x;
  if (i < NSLOT) atomicAdd(&counts[ei[i]], 1);
}

__global__ void k_scan(const int* __restrict__ counts, int* __restrict__ offsets,
                       int* __restrict__ fill){
  if (threadIdx.x == 0 && blockIdx.x == 0){
    int acc = 0;
    for (int e = 0; e < NEXP; e++){ offsets[e] = acc; fill[e] = acc; acc += counts[e]; }
  }
}

__global__ void k_assign(const int* __restrict__ ei, const float* __restrict__ ew,
                         int* __restrict__ fill, int* __restrict__ rowT,
                         float* __restrict__ rowC){
  int i = blockIdx.x * blockDim.x + threadIdx.x;
  if (i < NSLOT){
    int e = ei[i];
    int slot = atomicAdd(&fill[e], 1);
    rowT[slot] = i >> 1;       // token index (i = t*TOPK + k)
    rowC[slot] = ew[i];
  }
}

__global__ void k_gather(const float* __restrict__ x, const int* __restrict__ rowT,
                         unsigned short* __restrict__ Xg){
  int slot = blockIdx.x;
  int t = rowT[slot];
  int c = threadIdx.x * 4;
  float4 v = *(const float4*)(x + (size_t)t * HSZ + c);
  ushort4 o;
  o.x = f2bf(v.x); o.y = f2bf(v.y); o.z = f2bf(v.z); o.w = f2bf(v.w);
  *(ushort4*)(Xg + (size_t)slot * HSZ + c) = o;
}

// ---------------- weight transform: fp32 [R][C] -> bf16 [C][R] per expert ----
__global__ __launch_bounds__(256) void k_transpose(const float* __restrict__ src,
                                                   unsigned short* __restrict__ dst,
                                                   int R, int C){
  __shared__ unsigned short tile[64][65];
  const int tid = threadIdx.x;
  src += (size_t)blockIdx.z * R * C;
  dst += (size_t)blockIdx.z * R * C;
  const int r0 = blockIdx.y * 64, c0 = blockIdx.x * 64;
  #pragma unroll
  for (int p = 0; p < 4; p++){
    int r  = p * 16 + (tid >> 4);
    int cc = (tid & 15) * 4;
    float4 v = *(const float4*)(src + (size_t)(r0 + r) * C + c0 + cc);
    tile[r][cc]   = f2bf(v.x);
    tile[r][cc+1] = f2bf(v.y);
    tile[r][cc+2] = f2bf(v.z);
    tile[r][cc+3] = f2bf(v.w);
  }
  __syncthreads();
  #pragma unroll
  for (int p = 0; p < 4; p++){
    int c  = p * 16 + (tid >> 4);
    int rr = (tid & 15) * 4;
    ushort4 o;
    o.x = tile[rr][c]; o.y = tile[rr+1][c]; o.z = tile[rr+2][c]; o.w = tile[rr+3][c];
    *(ushort4*)(dst + (size_t)(c0 + c) * R + r0 + rr) = o;
  }
}

// ---------------- GEMM core (m97 recipe) ----------------
// A: bf16 [rows x K] k-contiguous, lda=K. B: bf16 [N x K] k-contiguous (pre-offset
// to row n0), ldb=K. Unpadded 128x32 LDS tiles, global_load_lds staging,
// ds_read_b128 frags. 4 waves 2x2, each 4x4 of 16x16x32 mfma.
__device__ inline void gemm_core(const unsigned short* __restrict__ Ag, int lda, int rows,
                                 const unsigned short* __restrict__ Bg, int ldb, int K,
                                 unsigned short* As, unsigned short* Bs,
                                 f32x4 acc[4][4])
{
  const int tid  = threadIdx.x;
  const int lane = tid & 63;
  const int wid  = tid >> 6;
  const int wm   = (wid & 1) * 64;
  const int wn   = (wid >> 1) * 64;
  const int q    = lane >> 4;
  const int l16  = lane & 15;

  for (int k0 = 0; k0 < K; k0 += BK){
    #pragma unroll
    for (int p = 0; p < 2; p++){
      int c  = (wid * 2 + p) * 64 + lane;   // chunk id, 16B each
      int r  = c >> 2;
      int kp = (c & 3) * 8;
      int ra = min(r, rows - 1);            // clamp tail (epilogue masks)
      async_copy16(Ag + (size_t)ra * lda + k0 + kp, As + (wid * 2 + p) * 512);
      async_copy16(Bg + (size_t)r  * ldb + k0 + kp, Bs + (wid * 2 + p) * 512);
    }
    __syncthreads();   // drains vmcnt before LDS use

    short8 af[4], bfr[4];
    #pragma unroll
    for (int i = 0; i < 4; i++)
      af[i] = *(const short8*)(As + (wm + i * 16 + l16) * BK + q * 8);
    #pragma unroll
    for (int j = 0; j < 4; j++)
      bfr[j] = *(const short8*)(Bs + (wn + j * 16 + l16) * BK + q * 8);

    #pragma unroll
    for (int i = 0; i < 4; i++)
      #pragma unroll
      for (int j = 0; j < 4; j++)
        acc[i][j] = __builtin_amdgcn_mfma_f32_16x16x32_bf16(af[i], bfr[j], acc[i][j], 0, 0, 0);
    __syncthreads();
  }
}

// ---------------- GEMM1: H = gelu(Xg @ Wt1[e]^T) ----------------
__global__ __launch_bounds__(256) void k_gemm1(const unsigned short* __restrict__ Xg,
                                               const unsigned short* __restrict__ Wt1,
                                               unsigned short* __restrict__ H,
                                               const int* __restrict__ counts,
                                               const int* __restrict__ offsets)
{
  __shared__ unsigned short As[BM * BK];
  __shared__ unsigned short Bs[BN * BK];
  const int e    = blockIdx.z;
  const int cnt  = counts[e];
  const int mblk = blockIdx.y;
  if (mblk * BM >= cnt) return;
  const int n0   = blockIdx.x * BN;
  const int row0 = offsets[e] + mblk * BM;
  const int rows = min(BM, cnt - mblk * BM);

  f32x4 acc[4][4] = {};
  gemm_core(Xg + (size_t)row0 * HSZ, HSZ, rows,
            Wt1 + (size_t)e * HSZ * FFND + (size_t)n0 * HSZ, HSZ, HSZ, As, Bs, acc);

  const int lane = threadIdx.x & 63, wid = threadIdx.x >> 6;
  const int wm = (wid & 1) * 64, wn = (wid >> 1) * 64;
  const int q = lane >> 4, l16 = lane & 15;
  #pragma unroll
  for (int i = 0; i < 4; i++)
    #pragma unroll
    for (int j = 0; j < 4; j++)
      #pragma unroll
      for (int r = 0; r < 4; r++){
        int row = wm + i * 16 + q * 4 + r;      // C/D: row=(lane>>4)*4+reg
        if (row < rows){
          int col = wn + j * 16 + l16;          // C/D: col=lane&15
          H[(size_t)(row0 + row) * FFND + n0 + col] = f2bf(gelu_tanh(acc[i][j][r]));
        }
      }
}

// ---------------- GEMM2: out[t] += coef * (H @ Wt2[e]^T) ----------------
__global__ __launch_bounds__(256) void k_gemm2(const unsigned short* __restrict__ H,
                                               const unsigned short* __restrict__ Wt2,
                                               float* __restrict__ out,
                                               const int* __restrict__ counts,
                                               const int* __restrict__ offsets,
                                               const int* __restrict__ rowT,
                                               const float* __restrict__ rowC)
{
  __shared__ unsigned short As[BM * BK];
  __shared__ unsigned short Bs[BN * BK];
  const int e    = blockIdx.z;
  const int cnt  = counts[e];
  const int mblk = blockIdx.y;
  if (mblk * BM >= cnt) return;
  const int n0   = blockIdx.x * BN;
  const int row0 = offsets[e] + mblk * BM;
  const int rows = min(BM, cnt - mblk * BM);

  f32x4 acc[4][4] = {};
  gemm_core(H + (size_t)row0 * FFND, FFND, rows,
            Wt2 + (size_t)e * FFND * HSZ + (size_t)n0 * FFND, FFND, FFND, As, Bs, acc);

  const int lane = threadIdx.x & 63, wid = threadIdx.x >> 6;
  const int wm = (wid & 1) * 64, wn = (wid >> 1) * 64;
  const int q = lane >> 4, l16 = lane & 15;
  #pragma unroll
  for (int i = 0; i < 4; i++)
    #pragma unroll
    for (int j = 0; j < 4; j++)
      #pragma unroll
      for (int r = 0; r < 4; r++){
        int row = wm + i * 16 + q * 4 + r;
        if (row < rows){
          int g = row0 + row;
          int col = wn + j * 16 + l16;
          atomicAdd(out + (size_t)rowT[g] * HSZ + n0 + col, rowC[g] * acc[i][j][r]);
        }
      }
}

// ---------------- launch ----------------
static inline size_t align_up(size_t v, size_t a){ return (v + a - 1) & ~(a - 1); }

extern "C" void kernel_launch(void* const* d_in, const int* in_sizes, int n_in,
                              void* d_out, int out_size, void* d_ws, size_t ws_size,
                              hipStream_t stream) {
  const float* x  = (const float*)d_in[0];
  const float* ew = (const float*)d_in[1];
  const int*   ei = (const int*)d_in[2];
  const float* w1 = (const float*)d_in[3];
  const float* w2 = (const float*)d_in[4];
  float* out = (float*)d_out;

  // workspace layout (bytes)
  char* base = (char*)d_ws;
  size_t off = 0;
  int* counts  = (int*)(base + off); off += 64;
  int* fill    = (int*)(base + off); off += 64;
  int* offsets = (int*)(base + off); off = align_up(off + 64, 4096);
  int* rowT    = (int*)(base + off); off += (size_t)NSLOT * 4;
  float* rowC  = (float*)(base + off); off = align_up(off + (size_t)NSLOT * 4, 1 << 20);
  unsigned short* Xg  = (unsigned short*)(base + off); off = align_up(off + (size_t)NSLOT * HSZ * 2, 1 << 20);
  unsigned short* H   = (unsigned short*)(base + off); off = align_up(off + (size_t)NSLOT * FFND * 2, 1 << 20);
  unsigned short* Wt1 = (unsigned short*)(base + off); off = align_up(off + (size_t)NEXP * HSZ * FFND * 2, 1 << 20);
  unsigned short* Wt2 = (unsigned short*)(base + off); off += (size_t)NEXP * FFND * HSZ * 2;
  (void)ws_size;

  hipMemsetAsync(d_out, 0, (size_t)out_size * sizeof(float), stream);
  hipMemsetAsync(counts, 0, 64, stream);

  k_count <<<NSLOT / 256, 256, 0, stream>>>(ei, counts);
  k_scan  <<<1, 64, 0, stream>>>(counts, offsets, fill);
  k_assign<<<NSLOT / 256, 256, 0, stream>>>(ei, ew, fill, rowT, rowC);
  k_gather<<<NSLOT, 256, 0, stream>>>(x, rowT, Xg);

  // weight transforms: w1 [HSZ][FFND] -> Wt1 [FFND][HSZ]; w2 [FFND][HSZ] -> Wt2 [HSZ][FFND]
  k_transpose<<<dim3(FFND / 64, HSZ / 64, NEXP), 256, 0, stream>>>(w1, Wt1, HSZ, FFND);
  k_transpose<<<dim3(HSZ / 64, FFND / 64, NEXP), 256, 0, stream>>>(w2, Wt2, FFND, HSZ);

  // worst case one expert owns all 8192 rows -> 64 m-blocks; extras early-exit
  k_gemm1<<<dim3(FFND / BN, 64, NEXP), 256, 0, stream>>>(Xg, Wt1, H, counts, offsets);
  k_gemm2<<<dim3(HSZ  / BN, 64, NEXP), 256, 0, stream>>>(H, Wt2, out, counts, offsets, rowT, rowC);
}